// Round 5
// baseline (380.512 us; speedup 1.0000x reference)
//
#include <hip/hip_runtime.h>
#include <hip/hip_bf16.h>

// Problem constants
#define BATCH   65536
#define HW      28
#define OHW     26
#define FEAT    676
#define HID     200
#define NCLS    10
#define MT2     64                  // images per gemm block (4 m-tiles)
#define GBLOCKS (BATCH / MT2)       // 1024
#define KC1     25                  // K-chunks for GEMM1: 784 -> 800 = 25*32

typedef __attribute__((ext_vector_type(8))) __bf16 bf16x8;
typedef __attribute__((ext_vector_type(4))) float  f32x4;

__device__ __forceinline__ unsigned int pk2(float a, float b) {
  __hip_bfloat16 ha = __float2bfloat16(a), hb = __float2bfloat16(b);
  return (unsigned int)__builtin_bit_cast(unsigned short, ha)
       | ((unsigned int)__builtin_bit_cast(unsigned short, hb) << 16);
}

// fslot: A-fragment layout with XOR swizzle, used ONLY for hidA.
//   element (m, k) at ((k>>5)*64 + ((k>>3)&3)*16 + (m ^ ((k>>5)&7)))*8 + (k&7)
__device__ __forceinline__ unsigned short* fslot(unsigned short* base, int m, int k) {
  const int kc = k >> 5;
  return base + ((kc * 64 + ((k >> 3) & 3) * 16 + (m ^ (kc & 7))) * 8) + (k & 7);
}

// ---------------------------------------------------------------------------
// prep_w1e: fold the 3x3 conv into w1.  W1eff[i][n] = sum_{di,dj valid}
//   cw[di*3+dj] * w1[(ri-di)*26+(ci-dj)][n],  i = ri*28+ci  (pixel index).
// Output in B-fragment order: chunk c = (kc*13+nt)*64 + qd*16 + ln holds
//   j=0..7 of k=kc*32+qd*8+j (K=784 padded to 800), n = nt*16+ln (pad 208).
// ---------------------------------------------------------------------------
__global__ __launch_bounds__(256) void prep_w1e(const float* __restrict__ w1,
                                                const float* __restrict__ cwp,
                                                unsigned short* __restrict__ w1e) {
  int c = blockIdx.x * 256 + threadIdx.x;
  if (c >= KC1 * 13 * 64) return;
  int lane = c & 63, g = c >> 6;
  int kc = g / 13, nt = g - kc * 13;
  int ln = lane & 15, qd = lane >> 4;
  int n = nt * 16 + ln;
  float cw[9];
  #pragma unroll
  for (int t = 0; t < 9; ++t) cw[t] = cwp[t];
  float v[8];
  #pragma unroll
  for (int j = 0; j < 8; ++j) {
    int k = kc * 32 + qd * 8 + j;
    float s = 0.f;
    if (k < 784 && n < HID) {
      int ri = k / 28, ci = k - ri * 28;
      #pragma unroll
      for (int di = 0; di < 3; ++di) {
        int r = ri - di;
        if (r >= 0 && r < OHW) {
          #pragma unroll
          for (int dj = 0; dj < 3; ++dj) {
            int cc = ci - dj;
            if (cc >= 0 && cc < OHW) s += cw[di * 3 + dj] * w1[(r * OHW + cc) * HID + n];
          }
        }
      }
    }
    v[j] = s;
  }
  uint4 o = make_uint4(pk2(v[0], v[1]), pk2(v[2], v[3]),
                       pk2(v[4], v[5]), pk2(v[6], v[7]));
  *(uint4*)(w1e + (size_t)c * 8) = o;
}

// w2 (200x10 f32) -> bf16 B-fragment order, K=224 N=16 padded. 7 KB.
__global__ __launch_bounds__(256) void prep_w2f(const float* __restrict__ w2,
                                                unsigned short* __restrict__ w2f) {
  int c = blockIdx.x * 256 + threadIdx.x;
  if (c >= 7 * 64) return;
  int lane = c & 63, kc = c >> 6;
  int col = lane & 15;
  float v[8];
  #pragma unroll
  for (int j = 0; j < 8; ++j) {
    int k = kc * 32 + (lane >> 4) * 8 + j;
    v[j] = (col < NCLS && k < HID) ? w2[k * NCLS + col] : 0.f;
  }
  uint4 o = make_uint4(pk2(v[0], v[1]), pk2(v[2], v[3]),
                       pk2(v[4], v[5]), pk2(v[6], v[7]));
  *(uint4*)(w2f + (size_t)c * 8) = o;
}

// ---------------------------------------------------------------------------
// fused5: block = 64 images. relu(x @ W1eff + b1) @ w2 + b2, conv pre-folded.
// A loaded DIRECTLY from x per lane (32B contiguous f32 -> 2x dwordx4 ->
// 4x pk2 cvt); no A-staging LDS, ZERO barriers in the K-loop. w1e rows
// k>=784 are zero, so tail garbage in A contributes nothing; only the
// very end of x needs an OOB guard (kc==24, qd>=2 -> zeros).
// Waves split N (13 tiles: 4/3/3/3); B reused across 4 m-tiles ->
// 16 MFMA per kc per wave, acc[4][NT].
// ---------------------------------------------------------------------------
template<int NT0, int NT>
__device__ __forceinline__ void gemm1_direct(
    const float* __restrict__ x, const unsigned short* __restrict__ w1e,
    const float* __restrict__ b1, unsigned short* hidA, int lane, int blk64) {
  const int ln = lane & 15, qd = lane >> 4;

  f32x4 acc[4][NT];
  #pragma unroll
  for (int mi = 0; mi < 4; ++mi)
    #pragma unroll
    for (int t = 0; t < NT; ++t) acc[mi][t] = (f32x4){0.f, 0.f, 0.f, 0.f};

  // per-m-tile base: lane reads x[image = blk64+mi*16+ln][kc*32 + qd*8 + j]
  const float* xa[4];
  #pragma unroll
  for (int mi = 0; mi < 4; ++mi)
    xa[mi] = x + ((size_t)(blk64 + mi * 16 + ln)) * 784 + qd * 8;

  #pragma unroll
  for (int kc = 0; kc < KC1; ++kc) {
    bf16x8 b[NT];
    #pragma unroll
    for (int t = 0; t < NT; ++t)
      b[t] = *(const bf16x8*)(w1e + ((size_t)(kc * 13 + NT0 + t) * 64 + lane) * 8);
    #pragma unroll
    for (int mi = 0; mi < 4; ++mi) {
      union { uint4 u; bf16x8 h; } cv;
      if (kc == KC1 - 1 && qd >= 2) {          // k>=784: avoid OOB at end of x
        cv.u = make_uint4(0u, 0u, 0u, 0u);
      } else {
        const float4 f0 = *(const float4*)(xa[mi] + kc * 32);
        const float4 f1 = *(const float4*)(xa[mi] + kc * 32 + 4);
        cv.u = make_uint4(pk2(f0.x, f0.y), pk2(f0.z, f0.w),
                          pk2(f1.x, f1.y), pk2(f1.z, f1.w));
      }
      #pragma unroll
      for (int t = 0; t < NT; ++t)
        acc[mi][t] = __builtin_amdgcn_mfma_f32_16x16x32_bf16(cv.h, b[t], acc[mi][t], 0, 0, 0);
    }
  }

  // epilogue: relu(acc + b1) -> bf16 hidA (fslot layout per m-tile)
  #pragma unroll
  for (int t = 0; t < NT; ++t) {
    const int n = (NT0 + t) * 16 + ln;
    if (n < HID) {
      const float bias = b1[n];
      const int kc2 = n >> 5, qd2 = (n >> 3) & 3, j2 = n & 7, c2 = kc2 & 7;
      #pragma unroll
      for (int mi = 0; mi < 4; ++mi)
        #pragma unroll
        for (int rr = 0; rr < 4; ++rr) {
          const int m = qd * 4 + rr;
          float h = fmaxf(acc[mi][t][rr] + bias, 0.f);
          __hip_bfloat16 hb = __float2bfloat16(h);
          hidA[mi * 3584 + (kc2 * 64 + qd2 * 16 + (m ^ c2)) * 8 + j2] =
              __builtin_bit_cast(unsigned short, hb);
        }
    }
  }
}

__global__ __launch_bounds__(256, 4) void fused5(
    const float* __restrict__ x, const unsigned short* __restrict__ w1e,
    const unsigned short* __restrict__ w2f, const float* __restrict__ b1,
    const float* __restrict__ b2, float* __restrict__ out) {
  __shared__ __align__(16) unsigned short hidA[4 * 7 * 64 * 8];   // 28,672 B
  const int tid  = threadIdx.x;
  const int wave = tid >> 6;
  const int lane = tid & 63;
  const int blk64 = blockIdx.x * MT2;

  // zero hid K-pad (k=200..223): 4 tiles x 16 rows x 12 dwords (untouched by epilogue)
  for (int i = tid; i < 768; i += 256) {
    int mi = i / 192, r = i - mi * 192, m = r / 12, d = r - m * 12;
    *(unsigned int*)fslot(hidA + mi * 3584, m, 200 + 2 * d) = 0u;
  }

  switch (wave) {
    case 0:  gemm1_direct<0, 4>(x, w1e, b1, hidA, lane, blk64); break;
    case 1:  gemm1_direct<4, 3>(x, w1e, b1, hidA, lane, blk64); break;
    case 2:  gemm1_direct<7, 3>(x, w1e, b1, hidA, lane, blk64); break;
    default: gemm1_direct<10, 3>(x, w1e, b1, hidA, lane, blk64); break;
  }
  __syncthreads();   // hidA complete (incl. pads) — the kernel's ONLY barrier

  // GEMM2: wave w handles m-tile w. 7 MFMA over K=224.
  const int ln = lane & 15, qd = lane >> 4;
  f32x4 acc2 = (f32x4){0.f, 0.f, 0.f, 0.f};
  #pragma unroll
  for (int kc = 0; kc < 7; ++kc) {
    bf16x8 a = *(const bf16x8*)&hidA[wave * 3584 + (kc * 64 + (lane ^ (kc & 7))) * 8];
    bf16x8 b = *(const bf16x8*)(w2f + ((size_t)kc * 64 + lane) * 8);
    acc2 = __builtin_amdgcn_mfma_f32_16x16x32_bf16(a, b, acc2, 0, 0, 0);
  }
  if (ln < NCLS) {
    const float bb = b2[ln];
    #pragma unroll
    for (int rr = 0; rr < 4; ++rr) {
      out[((size_t)(blockIdx.x * 4 + wave) * 16 + qd * 4 + rr) * NCLS + ln] = acc2[rr] + bb;
    }
  }
}

extern "C" void kernel_launch(void* const* d_in, const int* in_sizes, int n_in,
                              void* d_out, int out_size, void* d_ws, size_t ws_size,
                              hipStream_t stream) {
  const float* x  = (const float*)d_in[0];
  const float* cw = (const float*)d_in[1];
  const float* w1 = (const float*)d_in[2];
  const float* b1 = (const float*)d_in[3];
  const float* w2 = (const float*)d_in[4];
  const float* b2 = (const float*)d_in[5];
  float* out = (float*)d_out;

  unsigned short* w1e = (unsigned short*)d_ws;                      // 332,800 B
  unsigned short* w2f = (unsigned short*)((char*)d_ws + 335872);    //   7,168 B

  hipLaunchKernelGGL(prep_w1e, dim3((KC1 * 13 * 64 + 255) / 256), dim3(256), 0, stream,
                     w1, cw, w1e);
  hipLaunchKernelGGL(prep_w2f, dim3(2), dim3(256), 0, stream, w2, w2f);
  hipLaunchKernelGGL(fused5, dim3(GBLOCKS), dim3(256), 0, stream,
                     x, w1e, w2f, b1, b2, out);
}

// Round 6
// 320.928 us; speedup vs baseline: 1.1857x; 1.1857x over previous
//
#include <hip/hip_runtime.h>
#include <hip/hip_bf16.h>

// Problem constants
#define BATCH   65536
#define HW      28
#define OHW     26
#define FEAT    676
#define HID     200
#define NCLS    10
#define MT2     64                  // images per gemm block (4 m-tiles)
#define GBLOCKS (BATCH / MT2)       // 1024
#define KC1     25                  // K-chunks for GEMM1: 784 -> 800 = 25*32

typedef __attribute__((ext_vector_type(8))) __bf16 bf16x8;
typedef __attribute__((ext_vector_type(4))) float  f32x4;

// Raw workgroup barrier WITHOUT the vmcnt(0) drain __syncthreads() emits.
// lgkmcnt(0) makes this round's ds_writes visible; global prefetch loads
// (private regs, consumed next round after a compiler-counted vmcnt wait)
// stay IN FLIGHT across the barrier — the T3/T4 "never vmcnt(0) in the
// main loop" rule. "memory" clobber pins all memory ops on either side.
#define KBAR() asm volatile("s_waitcnt lgkmcnt(0)\n\ts_barrier" ::: "memory")

__device__ __forceinline__ unsigned int pk2(float a, float b) {
  __hip_bfloat16 ha = __float2bfloat16(a), hb = __float2bfloat16(b);
  return (unsigned int)__builtin_bit_cast(unsigned short, ha)
       | ((unsigned int)__builtin_bit_cast(unsigned short, hb) << 16);
}

// fslot: A-fragment layout with XOR swizzle, used ONLY for hidA.
//   element (m, k) at ((k>>5)*64 + ((k>>3)&3)*16 + (m ^ ((k>>5)&7)))*8 + (k&7)
__device__ __forceinline__ unsigned short* fslot(unsigned short* base, int m, int k) {
  const int kc = k >> 5;
  return base + ((kc * 64 + ((k >> 3) & 3) * 16 + (m ^ (kc & 7))) * 8) + (k & 7);
}

// ---------------------------------------------------------------------------
// prep_w1e: fold the 3x3 conv into w1.  W1eff[i][n] = sum_{di,dj valid}
//   cw[di*3+dj] * w1[(ri-di)*26+(ci-dj)][n],  i = ri*28+ci  (pixel index).
// Output in B-fragment order: chunk c = (kc*13+nt)*64 + qd*16 + ln holds
//   j=0..7 of k=kc*32+qd*8+j (K=784 padded to 800), n = nt*16+ln (pad 208).
// ---------------------------------------------------------------------------
__global__ __launch_bounds__(256) void prep_w1e(const float* __restrict__ w1,
                                                const float* __restrict__ cwp,
                                                unsigned short* __restrict__ w1e) {
  int c = blockIdx.x * 256 + threadIdx.x;
  if (c >= KC1 * 13 * 64) return;
  int lane = c & 63, g = c >> 6;
  int kc = g / 13, nt = g - kc * 13;
  int ln = lane & 15, qd = lane >> 4;
  int n = nt * 16 + ln;
  float cw[9];
  #pragma unroll
  for (int t = 0; t < 9; ++t) cw[t] = cwp[t];
  float v[8];
  #pragma unroll
  for (int j = 0; j < 8; ++j) {
    int k = kc * 32 + qd * 8 + j;
    float s = 0.f;
    if (k < 784 && n < HID) {
      int ri = k / 28, ci = k - ri * 28;
      #pragma unroll
      for (int di = 0; di < 3; ++di) {
        int r = ri - di;
        if (r >= 0 && r < OHW) {
          #pragma unroll
          for (int dj = 0; dj < 3; ++dj) {
            int cc = ci - dj;
            if (cc >= 0 && cc < OHW) s += cw[di * 3 + dj] * w1[(r * OHW + cc) * HID + n];
          }
        }
      }
    }
    v[j] = s;
  }
  uint4 o = make_uint4(pk2(v[0], v[1]), pk2(v[2], v[3]),
                       pk2(v[4], v[5]), pk2(v[6], v[7]));
  *(uint4*)(w1e + (size_t)c * 8) = o;
}

// w2 (200x10 f32) -> bf16 B-fragment order, K=224 N=16 padded. 7 KB.
__global__ __launch_bounds__(256) void prep_w2f(const float* __restrict__ w2,
                                                unsigned short* __restrict__ w2f) {
  int c = blockIdx.x * 256 + threadIdx.x;
  if (c >= 7 * 64) return;
  int lane = c & 63, kc = c >> 6;
  int col = lane & 15;
  float v[8];
  #pragma unroll
  for (int j = 0; j < 8; ++j) {
    int k = kc * 32 + (lane >> 4) * 8 + j;
    v[j] = (col < NCLS && k < HID) ? w2[k * NCLS + col] : 0.f;
  }
  uint4 o = make_uint4(pk2(v[0], v[1]), pk2(v[2], v[3]),
                       pk2(v[4], v[5]), pk2(v[6], v[7]));
  *(uint4*)(w2f + (size_t)c * 8) = o;
}

// ---------------------------------------------------------------------------
// fused6: identical to fused4 (R4, ~95us: staged-once A, N-split waves,
// double-buffered LDS, 16 MFMA/kc/wave) EXCEPT the 25 in-loop barriers are
// raw lgkm-only (KBAR) so the kc+1 prefetch global loads remain in flight
// across the barrier instead of being vmcnt(0)-drained every round.
// ---------------------------------------------------------------------------
template<int NT0, int NT>
__device__ __forceinline__ void gemm1_body(
    const float* __restrict__ x, const unsigned short* __restrict__ w1e,
    const float* __restrict__ b1, unsigned short* aBuf /*[2][4*512]*/,
    unsigned short* hidA, int lane, int tid, int blk64) {
  const int ln = lane & 15, qd = lane >> 4;

  // staging role: thread stages one 16B bf16 chunk (32B f32) per kc.
  const int sc_mi  = tid >> 6;
  const int sc_qd  = (tid >> 4) & 3;
  const int sc_row = tid & 15;
  const float* xrow = x + ((size_t)blk64 + sc_mi * 16 + sc_row) * 784 + sc_qd * 8;
  const int sc_off = (sc_mi * 64 + sc_qd * 16 + sc_row) * 8;   // shorts

  f32x4 acc[4][NT];
  #pragma unroll
  for (int mi = 0; mi < 4; ++mi)
    #pragma unroll
    for (int t = 0; t < NT; ++t) acc[mi][t] = (f32x4){0.f, 0.f, 0.f, 0.f};

  // prologue: stage kc=0 (full drain barrier once is fine here)
  {
    float4 f0 = *(const float4*)(xrow);
    float4 f1 = *(const float4*)(xrow + 4);
    *(uint4*)(aBuf + sc_off) = make_uint4(pk2(f0.x, f0.y), pk2(f0.z, f0.w),
                                          pk2(f1.x, f1.y), pk2(f1.z, f1.w));
  }
  __syncthreads();

  int cur = 0;
  for (int kc = 0; kc < KC1; ++kc) {
    // issue next-kc stage loads early (they stay in flight across KBAR)
    uint4 nx;
    const bool hav = (kc + 1 < KC1);
    if (hav) {
      if (kc + 1 == KC1 - 1 && sc_qd >= 2) {     // K-pad 784..800 -> zeros
        nx = make_uint4(0u, 0u, 0u, 0u);
      } else {
        float4 f0 = *(const float4*)(xrow + (kc + 1) * 32);
        float4 f1 = *(const float4*)(xrow + (kc + 1) * 32 + 4);
        nx = make_uint4(pk2(f0.x, f0.y), pk2(f0.z, f0.w),
                        pk2(f1.x, f1.y), pk2(f1.z, f1.w));
      }
    }
    // A-frags for the 4 m-tiles (linear, conflict-free b128)
    const unsigned short* ab = aBuf + cur * 2048;
    bf16x8 a[4];
    #pragma unroll
    for (int mi = 0; mi < 4; ++mi)
      a[mi] = *(const bf16x8*)(ab + mi * 512 + lane * 8);
    // B-frags + MFMA: b loaded once per n-tile, used by 4 m-tiles
    #pragma unroll
    for (int t = 0; t < NT; ++t) {
      bf16x8 b = *(const bf16x8*)(w1e + ((size_t)(kc * 13 + NT0 + t) * 64 + lane) * 8);
      #pragma unroll
      for (int mi = 0; mi < 4; ++mi)
        acc[mi][t] = __builtin_amdgcn_mfma_f32_16x16x32_bf16(a[mi], b, acc[mi][t], 0, 0, 0);
    }
    if (hav) *(uint4*)(aBuf + (cur ^ 1) * 2048 + sc_off) = nx;
    KBAR();                       // lgkm-only: prefetch loads NOT drained
    cur ^= 1;
  }

  // epilogue: relu(acc + b1) -> bf16 hidA (fslot layout per m-tile)
  #pragma unroll
  for (int t = 0; t < NT; ++t) {
    const int n = (NT0 + t) * 16 + ln;
    if (n < HID) {
      const float bias = b1[n];
      const int kc2 = n >> 5, qd2 = (n >> 3) & 3, j2 = n & 7, c2 = kc2 & 7;
      #pragma unroll
      for (int mi = 0; mi < 4; ++mi)
        #pragma unroll
        for (int rr = 0; rr < 4; ++rr) {
          const int m = qd * 4 + rr;
          float h = fmaxf(acc[mi][t][rr] + bias, 0.f);
          __hip_bfloat16 hb = __float2bfloat16(h);
          hidA[mi * 3584 + (kc2 * 64 + qd2 * 16 + (m ^ c2)) * 8 + j2] =
              __builtin_bit_cast(unsigned short, hb);
        }
    }
  }
}

__global__ __launch_bounds__(256, 4) void fused6(
    const float* __restrict__ x, const unsigned short* __restrict__ w1e,
    const unsigned short* __restrict__ w2f, const float* __restrict__ b1,
    const float* __restrict__ b2, float* __restrict__ out) {
  __shared__ __align__(16) unsigned short aBuf[2 * 4 * 64 * 8];   //  8,192 B
  __shared__ __align__(16) unsigned short hidA[4 * 7 * 64 * 8];   // 28,672 B -> 36.9 KB, 4 blk/CU
  const int tid  = threadIdx.x;
  const int wave = tid >> 6;
  const int lane = tid & 63;
  const int blk64 = blockIdx.x * MT2;

  // zero hid K-pad (k=200..223): 4 tiles x 16 rows x 12 dwords (untouched by epilogue)
  for (int i = tid; i < 768; i += 256) {
    int mi = i / 192, r = i - mi * 192, m = r / 12, d = r - m * 12;
    *(unsigned int*)fslot(hidA + mi * 3584, m, 200 + 2 * d) = 0u;
  }

  switch (wave) {
    case 0:  gemm1_body<0, 4>(x, w1e, b1, aBuf, hidA, lane, tid, blk64); break;
    case 1:  gemm1_body<4, 3>(x, w1e, b1, aBuf, hidA, lane, tid, blk64); break;
    case 2:  gemm1_body<7, 3>(x, w1e, b1, aBuf, hidA, lane, tid, blk64); break;
    default: gemm1_body<10, 3>(x, w1e, b1, aBuf, hidA, lane, tid, blk64); break;
  }
  __syncthreads();   // hidA complete (incl. pads) — full drain fine, once

  // GEMM2: wave w handles m-tile w. 7 MFMA over K=224.
  const int ln = lane & 15, qd = lane >> 4;
  f32x4 acc2 = (f32x4){0.f, 0.f, 0.f, 0.f};
  #pragma unroll
  for (int kc = 0; kc < 7; ++kc) {
    bf16x8 a = *(const bf16x8*)&hidA[wave * 3584 + (kc * 64 + (lane ^ (kc & 7))) * 8];
    bf16x8 b = *(const bf16x8*)(w2f + ((size_t)kc * 64 + lane) * 8);
    acc2 = __builtin_amdgcn_mfma_f32_16x16x32_bf16(a, b, acc2, 0, 0, 0);
  }
  if (ln < NCLS) {
    const float bb = b2[ln];
    #pragma unroll
    for (int rr = 0; rr < 4; ++rr) {
      out[((size_t)(blockIdx.x * 4 + wave) * 16 + qd * 4 + rr) * NCLS + ln] = acc2[rr] + bb;
    }
  }
}

extern "C" void kernel_launch(void* const* d_in, const int* in_sizes, int n_in,
                              void* d_out, int out_size, void* d_ws, size_t ws_size,
                              hipStream_t stream) {
  const float* x  = (const float*)d_in[0];
  const float* cw = (const float*)d_in[1];
  const float* w1 = (const float*)d_in[2];
  const float* b1 = (const float*)d_in[3];
  const float* w2 = (const float*)d_in[4];
  const float* b2 = (const float*)d_in[5];
  float* out = (float*)d_out;

  unsigned short* w1e = (unsigned short*)d_ws;                      // 332,800 B
  unsigned short* w2f = (unsigned short*)((char*)d_ws + 335872);    //   7,168 B

  hipLaunchKernelGGL(prep_w1e, dim3((KC1 * 13 * 64 + 255) / 256), dim3(256), 0, stream,
                     w1, cw, w1e);
  hipLaunchKernelGGL(prep_w2f, dim3(2), dim3(256), 0, stream, w2, w2f);
  hipLaunchKernelGGL(fused6, dim3(GBLOCKS), dim3(256), 0, stream,
                     x, w1e, w2f, b1, b2, out);
}